// Round 5
// baseline (222.286 us; speedup 1.0000x reference)
//
#include <hip/hip_runtime.h>
#include <hip/hip_cooperative_groups.h>
#include <math.h>

namespace cg = cooperative_groups;

#define BATCH 16384
#define DIM   64
#define KCODE 256

typedef unsigned short ushort_t;
typedef __attribute__((ext_vector_type(8))) short bf16x8;   // 8 bf16 (4 VGPR)
typedef __attribute__((ext_vector_type(4))) float f32x4;

#define MFMA16 __builtin_amdgcn_mfma_f32_16x16x32_bf16

static __device__ __forceinline__ float ss4(float4 a) {
    return a.x*a.x + a.y*a.y + a.z*a.z + a.w*a.w;
}
static __device__ __forceinline__ short f2bs(float f) {   // f32 -> bf16 RNE
    unsigned u = __float_as_uint(f);
    u += 0x7FFFu + ((u >> 16) & 1u);
    return (short)(u >> 16);
}
static __device__ __forceinline__ bf16x8 pack8(float4 a, float4 b, float s) {
    bf16x8 r;
    r[0]=f2bs(a.x*s); r[1]=f2bs(a.y*s); r[2]=f2bs(a.z*s); r[3]=f2bs(a.w*s);
    r[4]=f2bs(b.x*s); r[5]=f2bs(b.y*s); r[6]=f2bs(b.z*s); r[7]=f2bs(b.w*s);
    return r;
}

// Sinkhorn colsum over one phase's units. Unit = (m, 16-row tile). Recompute
// c via MFMA from bf16 An/Wl; FIRST: cs += sum_b E; else alpha from al (LDS),
// per-row beta via 4-bit butterfly; accumulate into block-local csl.
template<bool FIRST>
static __device__ __forceinline__ void sink_pass(
    const ushort_t* __restrict__ An, const short* __restrict__ Wl,
    const float* __restrict__ al, float* __restrict__ csl,
    int wid, int lane, int nW)
{
    for (int u = wid; u < 5120; u += nW) {
        const int m = u >> 10, rt = u & 1023;
        const int aset = (m==0) ? 0 : (m<3) ? 1 : (m==3) ? 2 : 3;
        const int wset = (m<2) ? 0 : 1;
        const ushort_t* ab = An + ((size_t)aset*BATCH + rt*16 + (lane&15))*DIM + (lane>>4)*8;
        bf16x8 af0 = *(const bf16x8*)ab;
        bf16x8 af1 = *(const bf16x8*)(ab + 32);
        float csp[16];
        if (FIRST) {
            #pragma unroll
            for (int kt=0;kt<16;++kt){
                bf16x8 wf0 = *(const bf16x8*)&Wl[((wset*2048)+(kt*2+0)*64+lane)*8];
                bf16x8 wf1 = *(const bf16x8*)&Wl[((wset*2048)+(kt*2+1)*64+lane)*8];
                f32x4 acc = {0.f,0.f,0.f,0.f};
                acc = MFMA16(af0, wf0, acc, 0,0,0);
                acc = MFMA16(af1, wf1, acc, 0,0,0);
                csp[kt] = __expf(20.f*acc[0]) + __expf(20.f*acc[1])
                        + __expf(20.f*acc[2]) + __expf(20.f*acc[3]);
            }
        } else {
            float ev[16][4];
            float sp0=0.f, sp1=0.f, sp2=0.f, sp3=0.f;
            #pragma unroll
            for (int kt=0;kt<16;++kt){
                bf16x8 wf0 = *(const bf16x8*)&Wl[((wset*2048)+(kt*2+0)*64+lane)*8];
                bf16x8 wf1 = *(const bf16x8*)&Wl[((wset*2048)+(kt*2+1)*64+lane)*8];
                f32x4 acc = {0.f,0.f,0.f,0.f};
                acc = MFMA16(af0, wf0, acc, 0,0,0);
                acc = MFMA16(af1, wf1, acc, 0,0,0);
                ev[kt][0]=__expf(20.f*acc[0]); ev[kt][1]=__expf(20.f*acc[1]);
                ev[kt][2]=__expf(20.f*acc[2]); ev[kt][3]=__expf(20.f*acc[3]);
                const float a = al[m*KCODE + kt*16 + (lane&15)];
                sp0 = fmaf(a, ev[kt][0], sp0);
                sp1 = fmaf(a, ev[kt][1], sp1);
                sp2 = fmaf(a, ev[kt][2], sp2);
                sp3 = fmaf(a, ev[kt][3], sp3);
            }
            #pragma unroll
            for (int off=8; off>=1; off>>=1){
                sp0 += __shfl_xor(sp0, off, 64);
                sp1 += __shfl_xor(sp1, off, 64);
                sp2 += __shfl_xor(sp2, off, 64);
                sp3 += __shfl_xor(sp3, off, 64);
            }
            const float b0 = __builtin_amdgcn_rcpf(16384.f*sp0);
            const float b1 = __builtin_amdgcn_rcpf(16384.f*sp1);
            const float b2 = __builtin_amdgcn_rcpf(16384.f*sp2);
            const float b3 = __builtin_amdgcn_rcpf(16384.f*sp3);
            #pragma unroll
            for (int kt=0;kt<16;++kt)
                csp[kt] = ev[kt][0]*b0 + ev[kt][1]*b1 + ev[kt][2]*b2 + ev[kt][3]*b3;
        }
        // flush unit: reduce the 4 row-groups, deposit k = kt*16 + lane (lane<16)
        #pragma unroll
        for (int kt=0;kt<16;++kt){
            float v = csp[kt];
            v += __shfl_xor(v, 16, 64);
            v += __shfl_xor(v, 32, 64);
            if (lane < 16) atomicAdd(&csl[m*KCODE + kt*16 + lane], v);
        }
    }
}

// ---------------------------------------------------------------------------
// One cooperative kernel, 5 phases separated by grid.sync().
// LDS: Wl 64K (both W sets, frag-linear, staged once) + al 5K + csl 5K.
// ---------------------------------------------------------------------------
__global__ __launch_bounds__(256, 2) void cla_mega(
    const float* __restrict__ ue, const float* __restrict__ ie,
    const float* __restrict__ me, const float* __restrict__ te,
    const int* __restrict__ users, const int* __restrict__ items,
    const float* __restrict__ wfeat, const float* __restrict__ wii,
    ushort_t* __restrict__ An, ushort_t* __restrict__ Wn,
    float* __restrict__ cs, const float* __restrict__ gamma_p,
    float* __restrict__ out)
{
    cg::grid_group gg = cg::this_grid();
    const int t = threadIdx.x, lane = t & 63;
    const int g = blockIdx.x*256 + t;
    const int wid = (blockIdx.x*256 + t) >> 6;
    const int nT = gridDim.x << 8;
    const int nW = gridDim.x << 2;

    __shared__ short Wl[32768];   // 64 KB
    __shared__ float al[1280];    // 5 KB
    __shared__ float csl[1280];   // 5 KB

    // ================= phase 0: zero cs/out, prep An (gather+l2norm+bf16), Wn
    for (int i = g; i < 3840; i += nT) cs[i] = 0.f;
    if (g == 0) out[0] = 0.f;

    for (int h = g; h < 2*4*BATCH; h += nT) {      // 2 threads per A row
        const int row = h >> 1, half = h & 1;
        const int set = row >> 14, r = row & (BATCH-1);
        const float* src; int idx;
        if (set == 0)      { src = ue; idx = users[r]; }
        else if (set == 1) { src = ie; idx = items[r]; }
        else if (set == 2) { src = me; idx = items[r]; }
        else               { src = te; idx = items[r]; }
        const float4* p = (const float4*)(src + (size_t)idx*DIM + half*32);
        float4 q[8]; float ss = 0.f;
        #pragma unroll
        for (int i2=0;i2<8;++i2){ q[i2]=p[i2]; ss += ss4(q[i2]); }
        ss += __shfl_xor(ss, 1, 64);
        const float inv = 1.0f / fmaxf(sqrtf(ss), 1e-12f);
        ushort_t* dst = An + ((size_t)set*BATCH + r)*DIM + half*32;
        #pragma unroll
        for (int j=0;j<4;++j)
            *(bf16x8*)(dst + j*8) = pack8(q[2*j], q[2*j+1], inv);
    }
    for (int h = g; h < 2*2*KCODE; h += nT) {      // 2 threads per W row
        const int wrow = h >> 1, half = h & 1;
        const int wset = wrow >> 8, wr = wrow & 255;
        const float* src = (wset ? wii : wfeat) + (size_t)wr*DIM + half*32;
        const float4* p = (const float4*)src;
        float4 q[8]; float ss = 0.f;
        #pragma unroll
        for (int i2=0;i2<8;++i2){ q[i2]=p[i2]; ss += ss4(q[i2]); }
        ss += __shfl_xor(ss, 1, 64);
        const float inv = 1.0f / fmaxf(sqrtf(ss), 1e-12f);
        ushort_t* dst = Wn + ((size_t)wset*KCODE + wr)*DIM + half*32;
        #pragma unroll
        for (int j=0;j<4;++j)
            *(bf16x8*)(dst + j*8) = pack8(q[2*j], q[2*j+1], inv);
    }
    gg.sync();

    // ---- stage both W sets into LDS, frag-linear (once, reused all phases)
    for (int cid = t; cid < 4096; cid += 256) {
        const int ws2 = cid >> 11, rem = cid & 2047;
        const int kt = rem >> 7, kk = (rem >> 6) & 1, ln = rem & 63;
        const ushort_t* s2 = Wn + ((size_t)ws2*KCODE + kt*16 + (ln&15))*DIM
                                + kk*32 + (ln>>4)*8;
        *(bf16x8*)&Wl[cid*8] = *(const bf16x8*)s2;
    }
    #pragma unroll
    for (int j=0;j<5;++j) csl[j*256+t] = 0.f;
    __syncthreads();

    // ================= phase 1: cs1 (beta0 == 1)
    sink_pass<true>(An, Wl, al, csl, wid, lane, nW);
    __syncthreads();
    #pragma unroll
    for (int j=0;j<5;++j) atomicAdd(&cs[j*256+t], csl[j*256+t]);
    gg.sync();

    // ================= phase 2: cs2
    #pragma unroll
    for (int j=0;j<5;++j){
        al[j*256+t]  = __builtin_amdgcn_rcpf(256.0f * cs[j*256+t]);
        csl[j*256+t] = 0.f;
    }
    __syncthreads();
    sink_pass<false>(An, Wl, al, csl, wid, lane, nW);
    __syncthreads();
    #pragma unroll
    for (int j=0;j<5;++j) atomicAdd(&cs[1280 + j*256+t], csl[j*256+t]);
    gg.sync();

    // ================= phase 3: cs3
    #pragma unroll
    for (int j=0;j<5;++j){
        al[j*256+t]  = __builtin_amdgcn_rcpf(256.0f * cs[1280 + j*256+t]);
        csl[j*256+t] = 0.f;
    }
    __syncthreads();
    sink_pass<false>(An, Wl, al, csl, wid, lane, nW);
    __syncthreads();
    #pragma unroll
    for (int j=0;j<5;++j) atomicAdd(&cs[2560 + j*256+t], csl[j*256+t]);
    gg.sync();

    // ================= phase 4: fused CE
    #pragma unroll
    for (int j=0;j<5;++j)
        al[j*256+t] = __builtin_amdgcn_rcpf(256.0f * cs[2560 + j*256+t]);
    __syncthreads();

    const float gam = fminf(fmaxf(gamma_p[0], 0.01f), 0.99f);
    const float invg = 1.0f / gam;
    float wacc = 0.f;
    for (int rt = wid; rt < 1024; rt += nW) {
        const int r0 = rt*16;
        bf16x8 af[4][2];
        #pragma unroll
        for (int s=0;s<4;++s){
            const ushort_t* ab = An + ((size_t)s*BATCH + r0 + (lane&15))*DIM + (lane>>4)*8;
            af[s][0] = *(const bf16x8*)ab;
            af[s][1] = *(const bf16x8*)(ab + 32);
        }
        float S[5][4], L[5][4], DP[5][4];
        #pragma unroll
        for (int mm=0;mm<5;++mm)
            #pragma unroll
            for (int r=0;r<4;++r){ S[mm][r]=0.f; L[mm][r]=0.f; DP[mm][r]=0.f; }

        #pragma unroll 2
        for (int kt=0;kt<16;++kt){
            bf16x8 wf[2][2];
            #pragma unroll
            for (int ws2=0;ws2<2;++ws2){
                wf[ws2][0] = *(const bf16x8*)&Wl[((ws2*2048)+(kt*2+0)*64+lane)*8];
                wf[ws2][1] = *(const bf16x8*)&Wl[((ws2*2048)+(kt*2+1)*64+lane)*8];
            }
            const f32x4 Z = {0.f,0.f,0.f,0.f};
            f32x4 c[5];
            c[0] = MFMA16(af[0][0], wf[0][0], Z, 0,0,0);
            c[0] = MFMA16(af[0][1], wf[0][1], c[0], 0,0,0);
            c[1] = MFMA16(af[1][0], wf[0][0], Z, 0,0,0);
            c[1] = MFMA16(af[1][1], wf[0][1], c[1], 0,0,0);
            c[2] = MFMA16(af[1][0], wf[1][0], Z, 0,0,0);
            c[2] = MFMA16(af[1][1], wf[1][1], c[2], 0,0,0);
            c[3] = MFMA16(af[2][0], wf[1][0], Z, 0,0,0);
            c[3] = MFMA16(af[2][1], wf[1][1], c[3], 0,0,0);
            c[4] = MFMA16(af[3][0], wf[1][0], Z, 0,0,0);
            c[4] = MFMA16(af[3][1], wf[1][1], c[4], 0,0,0);

            float am[5];
            #pragma unroll
            for (int mm=0;mm<5;++mm) am[mm] = al[mm*KCODE + kt*16 + (lane&15)];

            float fm[5][4];
            #pragma unroll
            for (int mm=0;mm<5;++mm)
                #pragma unroll
                for (int r=0;r<4;++r){
                    const float cv = c[mm][r];
                    const float f = am[mm] * __expf(20.f*cv);
                    fm[mm][r] = f;
                    S[mm][r] += f;
                    L[mm][r] += __expf(invg*cv);
                }
            #pragma unroll
            for (int r=0;r<4;++r){
                DP[0][r] = fmaf(fm[0][r], c[1][r], DP[0][r]);
                DP[1][r] = fmaf(fm[1][r], c[0][r], DP[1][r]);
                const float c34 = c[3][r]+c[4][r];
                const float c24 = c[2][r]+c[4][r];
                const float c23 = c[2][r]+c[3][r];
                DP[2][r] = fmaf(fm[2][r], c34, DP[2][r]);
                DP[3][r] = fmaf(fm[3][r], c24, DP[3][r]);
                DP[4][r] = fmaf(fm[4][r], c23, DP[4][r]);
            }
        }
        #pragma unroll
        for (int off=8; off>=1; off>>=1)
            #pragma unroll
            for (int mm=0;mm<5;++mm)
                #pragma unroll
                for (int r=0;r<4;++r){
                    S[mm][r]  += __shfl_xor(S[mm][r],  off, 64);
                    L[mm][r]  += __shfl_xor(L[mm][r],  off, 64);
                    DP[mm][r] += __shfl_xor(DP[mm][r], off, 64);
                }
        #pragma unroll
        for (int r=0;r<4;++r){
            const float u =
                0.5f*(DP[0][r]*__builtin_amdgcn_rcpf(S[0][r])
                    + DP[1][r]*__builtin_amdgcn_rcpf(S[1][r]))
              + (1.f/6.f)*(DP[2][r]*__builtin_amdgcn_rcpf(S[2][r])
                         + DP[3][r]*__builtin_amdgcn_rcpf(S[3][r])
                         + DP[4][r]*__builtin_amdgcn_rcpf(S[4][r]));
            const float Lr =
                0.5f*(__logf(L[0][r]) + __logf(L[1][r]))
              + (1.f/3.f)*(__logf(L[2][r]) + __logf(L[3][r]) + __logf(L[4][r]));
            wacc += Lr - invg*u;
        }
    }
    wacc += __shfl_xor(wacc, 16, 64);
    wacc += __shfl_xor(wacc, 32, 64);
    if (lane == 0) atomicAdd(out, wacc * (1.0f/16384.0f));
}

// ---------------------------------------------------------------------------
extern "C" void kernel_launch(void* const* d_in, const int* in_sizes, int n_in,
                              void* d_out, int out_size, void* d_ws, size_t ws_size,
                              hipStream_t stream)
{
    const float* ue    = (const float*)d_in[0];
    const float* ie    = (const float*)d_in[1];
    const float* me    = (const float*)d_in[2];
    const float* te    = (const float*)d_in[3];
    const int*   users = (const int*)d_in[4];
    const int*   items = (const int*)d_in[5];
    const float* wfeat = (const float*)d_in[6];
    const float* wii   = (const float*)d_in[7];
    const float* gamma = (const float*)d_in[8];
    float* out = (float*)d_out;

    // ws: An bf16 [4][16384][64] (8MB) | Wn bf16 [2][256][64] | cs[3][1280] f32
    ushort_t* An = (ushort_t*)d_ws;
    ushort_t* Wn = An + (size_t)4*BATCH*DIM;
    float* cs = (float*)(Wn + 2*KCODE*DIM);

    int maxPerCU = 0;
    hipOccupancyMaxActiveBlocksPerMultiprocessor(&maxPerCU, cla_mega, 256, 0);
    int nBlk = (maxPerCU > 0 ? maxPerCU : 1) * 256;   // 256 CUs on MI355X
    if (nBlk > 512) nBlk = 512;

    void* args[] = { (void*)&ue, (void*)&ie, (void*)&me, (void*)&te,
                     (void*)&users, (void*)&items, (void*)&wfeat, (void*)&wii,
                     (void*)&An, (void*)&Wn, (void*)&cs, (void*)&gamma,
                     (void*)&out };
    hipLaunchCooperativeKernel(cla_mega, dim3(nBlk), dim3(256), args, 0, stream);
}

// Round 6
// 146.535 us; speedup vs baseline: 1.5169x; 1.5169x over previous
//
#include <hip/hip_runtime.h>
#include <hip/hip_bf16.h>
#include <math.h>

#define BATCH 16384
#define DIM   64
#define KCODE 256

typedef unsigned short ushort_t;
typedef __attribute__((ext_vector_type(8))) short bf16x8;   // 8 bf16 (4 VGPR)
typedef __attribute__((ext_vector_type(4))) float f32x4;

#define MFMA16 __builtin_amdgcn_mfma_f32_16x16x32_bf16

static __device__ __forceinline__ float ss4(float4 a) {
    return a.x*a.x + a.y*a.y + a.z*a.z + a.w*a.w;
}
static __device__ __forceinline__ short f2bs(float f) {   // f32 -> bf16 RNE
    unsigned u = __float_as_uint(f);
    u += 0x7FFFu + ((u >> 16) & 1u);
    return (short)(u >> 16);
}
static __device__ __forceinline__ bf16x8 pack8(float4 a, float4 b, float s) {
    bf16x8 r;
    r[0]=f2bs(a.x*s); r[1]=f2bs(a.y*s); r[2]=f2bs(a.z*s); r[3]=f2bs(a.w*s);
    r[4]=f2bs(b.x*s); r[5]=f2bs(b.y*s); r[6]=f2bs(b.z*s); r[7]=f2bs(b.w*s);
    return r;
}

// ---------------------------------------------------------------------------
// K1: gather + l2norm(A) -> bf16 A_norm; l2norm(W) -> bf16 W_norm; MFMA GEMM
// of this block's 64 rows; Sinkhorn colsum #1 (cs1[k] += sum_b exp(20c)).
// grid (256, 5): x = 64-row block, y = matrix. LDS: W 32K frag-linear + A 8K.
// ---------------------------------------------------------------------------
__global__ __launch_bounds__(256) void k1_prep_gemm_cs1(
    const float* __restrict__ ue, const float* __restrict__ ie,
    const float* __restrict__ me, const float* __restrict__ te,
    const int* __restrict__ users, const int* __restrict__ items,
    const float* __restrict__ wfeat, const float* __restrict__ wii,
    ushort_t* __restrict__ An, ushort_t* __restrict__ Wn,
    float* __restrict__ cs1)
{
    const int m  = blockIdx.y;
    const int bx = blockIdx.x;
    const int t  = threadIdx.x;
    const int aset = (m==0) ? 0 : (m<3) ? 1 : (m==3) ? 2 : 3;
    const int wset = (m<2) ? 0 : 1;
    const float* asrc = (aset==0)?ue:(aset==1)?ie:(aset==2)?me:te;
    const int*  idxv = (m==0)?users:items;
    const float* wsrc = (wset==0)?wfeat:wii;
    const bool store_w = ((m==0 || m==2) && bx==0);
    const bool store_a = (m != 2);     // m=1 already stores set 1

    __shared__ short Wl[16384];   // 2048 fragment chunks * 8 bf16 (32 KB)
    __shared__ short Al[4096];    // 512 chunks (8 KB)
    __shared__ float redA[4][64];
    __shared__ float csl[256];

    // ---- W: thread t owns W row t: load f32, normalize, pack to frag-linear LDS
    {
        const float4* wp = (const float4*)(wsrc + t*DIM);
        float4 q[16]; float ss = 0.f;
        #pragma unroll
        for (int i=0;i<16;++i){ q[i]=wp[i]; ss += ss4(q[i]); }
        const float inv = 1.0f / fmaxf(sqrtf(ss), 1e-12f);
        const int kt = t>>4, lr = t&15;
        #pragma unroll
        for (int kk=0;kk<2;++kk)
            #pragma unroll
            for (int fs=0;fs<4;++fs){
                const int qi = kk*8 + fs*2;
                bf16x8 pk = pack8(q[qi], q[qi+1], inv);
                const int cid = (kt*2+kk)*64 + fs*16 + lr;
                *(bf16x8*)&Wl[cid*8] = pk;
                if (store_w)
                    *(bf16x8*)(Wn + ((size_t)wset*KCODE + t)*DIM + kk*32 + fs*8) = pk;
            }
    }

    // ---- A: thread t -> row rb = t&63 of this block, d-segment seg = t>>6
    const int rb = t&63, seg = t>>6;
    const int gidx = idxv[bx*64 + rb];
    const float4* ap = (const float4*)(asrc + (size_t)gidx*DIM + seg*16);
    float4 a0=ap[0], a1=ap[1], a2=ap[2], a3=ap[3];
    redA[seg][rb] = ss4(a0)+ss4(a1)+ss4(a2)+ss4(a3);
    csl[t] = 0.f;
    __syncthreads();

    {
        const float tot = redA[0][rb]+redA[1][rb]+redA[2][rb]+redA[3][rb];
        const float inv = 1.0f/fmaxf(sqrtf(tot),1e-12f);
        bf16x8 c0 = pack8(a0, a1, inv);       // d = seg*16 .. +7
        bf16x8 c1 = pack8(a2, a3, inv);       // d = seg*16+8 .. +15
        const int kk = seg>>1, fs0 = (seg&1)*2;
        const int base = ((rb>>4)*2 + kk)*64;
        *(bf16x8*)&Al[(base + fs0*16     + (rb&15))*8] = c0;
        *(bf16x8*)&Al[(base + (fs0+1)*16 + (rb&15))*8] = c1;
        if (store_a) {
            ushort_t* dst = An + ((size_t)aset*BATCH + bx*64 + rb)*DIM + seg*16;
            *(bf16x8*)dst       = c0;
            *(bf16x8*)(dst + 8) = c1;
        }
    }
    __syncthreads();

    // ---- GEMM: wave w owns 16-row tile w; cs1 colsum of exp(20c) ----
    const int w = t>>6, lane = t&63;
    bf16x8 af0 = *(bf16x8*)&Al[((w*2+0)*64 + lane)*8];
    bf16x8 af1 = *(bf16x8*)&Al[((w*2+1)*64 + lane)*8];
    #pragma unroll 4
    for (int kt=0; kt<16; ++kt){
        bf16x8 wf0 = *(bf16x8*)&Wl[((kt*2+0)*64 + lane)*8];
        bf16x8 wf1 = *(bf16x8*)&Wl[((kt*2+1)*64 + lane)*8];
        f32x4 acc = {0.f,0.f,0.f,0.f};
        acc = MFMA16(af0, wf0, acc, 0,0,0);
        acc = MFMA16(af1, wf1, acc, 0,0,0);
        float es = __expf(20.f*acc[0]) + __expf(20.f*acc[1])
                 + __expf(20.f*acc[2]) + __expf(20.f*acc[3]);
        atomicAdd(&csl[kt*16 + (lane&15)], es);
    }
    __syncthreads();
    atomicAdd(&cs1[m*KCODE + t], csl[t]);
}

// ---------------------------------------------------------------------------
// K2/K3: Sinkhorn pass p>=2. Recompute c via MFMA; alpha inline from cs_prev;
// per-row s = sum alpha*E (4-shfl butterfly); beta = 1/(B*s);
// cs_next[k] += sum_b E*beta.  grid (128, 5).
// ---------------------------------------------------------------------------
__global__ __launch_bounds__(256) void k_pass(
    const ushort_t* __restrict__ An, const ushort_t* __restrict__ Wn,
    const float* __restrict__ cs_prev, float* __restrict__ cs_next)
{
    const int m = blockIdx.y;
    const int aset = (m==0)?0:(m<3)?1:(m==3)?2:3;
    const int wset = (m<2)?0:1;
    const int t = threadIdx.x, lane = t&63, w = t>>6;

    __shared__ short Wl[16384];
    __shared__ float csl[256];

    #pragma unroll
    for (int c8=0;c8<8;++c8){
        const int cid = c8*256 + t;
        const int kt = cid>>7, kk=(cid>>6)&1, ln=cid&63;
        const ushort_t* src = Wn + ((size_t)wset*KCODE + kt*16 + (ln&15))*DIM
                                 + kk*32 + (ln>>4)*8;
        *(bf16x8*)&Wl[cid*8] = *(const bf16x8*)src;
    }
    csl[t] = 0.f;
    float ar[16];
    #pragma unroll
    for (int kt=0;kt<16;++kt)
        ar[kt] = __builtin_amdgcn_rcpf(256.0f * cs_prev[m*KCODE + kt*16 + (lane&15)]);
    __syncthreads();

    float csp[16];
    #pragma unroll
    for (int kt=0;kt<16;++kt) csp[kt]=0.f;

    for (int rt = blockIdx.x*4 + w; rt < BATCH/16; rt += gridDim.x*4){
        const int r0 = rt*16;
        const ushort_t* ab = An + ((size_t)aset*BATCH + r0 + (lane&15))*DIM + (lane>>4)*8;
        bf16x8 af0 = *(const bf16x8*)ab;
        bf16x8 af1 = *(const bf16x8*)(ab + 32);
        float ev[16][4];
        float sp0=0.f, sp1=0.f, sp2=0.f, sp3=0.f;
        #pragma unroll
        for (int kt=0;kt<16;++kt){
            bf16x8 wf0 = *(bf16x8*)&Wl[((kt*2+0)*64+lane)*8];
            bf16x8 wf1 = *(bf16x8*)&Wl[((kt*2+1)*64+lane)*8];
            f32x4 acc = {0.f,0.f,0.f,0.f};
            acc = MFMA16(af0, wf0, acc, 0,0,0);
            acc = MFMA16(af1, wf1, acc, 0,0,0);
            ev[kt][0]=__expf(20.f*acc[0]); ev[kt][1]=__expf(20.f*acc[1]);
            ev[kt][2]=__expf(20.f*acc[2]); ev[kt][3]=__expf(20.f*acc[3]);
            sp0 = fmaf(ar[kt], ev[kt][0], sp0);
            sp1 = fmaf(ar[kt], ev[kt][1], sp1);
            sp2 = fmaf(ar[kt], ev[kt][2], sp2);
            sp3 = fmaf(ar[kt], ev[kt][3], sp3);
        }
        #pragma unroll
        for (int off=8; off>=1; off>>=1){
            sp0 += __shfl_xor(sp0, off, 64);
            sp1 += __shfl_xor(sp1, off, 64);
            sp2 += __shfl_xor(sp2, off, 64);
            sp3 += __shfl_xor(sp3, off, 64);
        }
        const float b0 = __builtin_amdgcn_rcpf(16384.f*sp0);
        const float b1 = __builtin_amdgcn_rcpf(16384.f*sp1);
        const float b2 = __builtin_amdgcn_rcpf(16384.f*sp2);
        const float b3 = __builtin_amdgcn_rcpf(16384.f*sp3);
        #pragma unroll
        for (int kt=0;kt<16;++kt)
            csp[kt] += ev[kt][0]*b0 + ev[kt][1]*b1 + ev[kt][2]*b2 + ev[kt][3]*b3;
    }
    #pragma unroll
    for (int kt=0;kt<16;++kt)
        atomicAdd(&csl[kt*16 + (lane&15)], csp[kt]);
    __syncthreads();
    atomicAdd(&cs_next[m*KCODE + t], csl[t]);
}

// ---------------------------------------------------------------------------
// K4: CE. Recompute all 5 c-tiles per kt; accumulate per-lane partials of
// s_m (alpha*E), l_m (exp(c/g)), dp_m (alpha*E*cc_m); one butterfly set per
// 16-row tile; loss deposited once per wave.  grid (256).
// ---------------------------------------------------------------------------
__global__ __launch_bounds__(256) void k_ce(
    const ushort_t* __restrict__ An, const ushort_t* __restrict__ Wn,
    const float* __restrict__ cs3, const float* __restrict__ gamma_p,
    float* __restrict__ out)
{
    const int t = threadIdx.x, lane = t&63, w = t>>6;
    __shared__ short Wl[32768];   // both wsets, 64 KB
    __shared__ float al[1280];

    #pragma unroll
    for (int c16=0;c16<16;++c16){
        const int cid = c16*256 + t;
        const int ws = cid>>11, rem = cid&2047;
        const int kt = rem>>7, kk=(rem>>6)&1, ln=rem&63;
        const ushort_t* src = Wn + ((size_t)ws*KCODE + kt*16 + (ln&15))*DIM
                                 + kk*32 + (ln>>4)*8;
        *(bf16x8*)&Wl[cid*8] = *(const bf16x8*)src;
    }
    #pragma unroll
    for (int mm=0;mm<5;++mm)
        al[mm*256+t] = __builtin_amdgcn_rcpf(256.0f * cs3[mm*KCODE + t]);
    const float g = fminf(fmaxf(gamma_p[0], 0.01f), 0.99f);
    const float invg = 1.0f/g;
    __syncthreads();

    float wacc = 0.f;
    for (int rt = blockIdx.x*4 + w; rt < BATCH/16; rt += gridDim.x*4){
        const int r0 = rt*16;
        bf16x8 af[4][2];
        #pragma unroll
        for (int s=0;s<4;++s){
            const ushort_t* ab = An + ((size_t)s*BATCH + r0 + (lane&15))*DIM + (lane>>4)*8;
            af[s][0] = *(const bf16x8*)ab;
            af[s][1] = *(const bf16x8*)(ab + 32);
        }
        float S[5][4], L[5][4], DP[5][4];
        #pragma unroll
        for (int mm=0;mm<5;++mm)
            #pragma unroll
            for (int r=0;r<4;++r){ S[mm][r]=0.f; L[mm][r]=0.f; DP[mm][r]=0.f; }

        #pragma unroll 2
        for (int kt=0;kt<16;++kt){
            bf16x8 wf[2][2];
            #pragma unroll
            for (int ws=0;ws<2;++ws){
                wf[ws][0] = *(bf16x8*)&Wl[((ws*2048) + (kt*2+0)*64 + lane)*8];
                wf[ws][1] = *(bf16x8*)&Wl[((ws*2048) + (kt*2+1)*64 + lane)*8];
            }
            const f32x4 Z = {0.f,0.f,0.f,0.f};
            f32x4 c[5];
            c[0] = MFMA16(af[0][0], wf[0][0], Z, 0,0,0);
            c[0] = MFMA16(af[0][1], wf[0][1], c[0], 0,0,0);
            c[1] = MFMA16(af[1][0], wf[0][0], Z, 0,0,0);
            c[1] = MFMA16(af[1][1], wf[0][1], c[1], 0,0,0);
            c[2] = MFMA16(af[1][0], wf[1][0], Z, 0,0,0);
            c[2] = MFMA16(af[1][1], wf[1][1], c[2], 0,0,0);
            c[3] = MFMA16(af[2][0], wf[1][0], Z, 0,0,0);
            c[3] = MFMA16(af[2][1], wf[1][1], c[3], 0,0,0);
            c[4] = MFMA16(af[3][0], wf[1][0], Z, 0,0,0);
            c[4] = MFMA16(af[3][1], wf[1][1], c[4], 0,0,0);

            float am[5];
            #pragma unroll
            for (int mm=0;mm<5;++mm) am[mm] = al[mm*256 + kt*16 + (lane&15)];

            float fm[5][4];
            #pragma unroll
            for (int mm=0;mm<5;++mm)
                #pragma unroll
                for (int r=0;r<4;++r){
                    const float cv = c[mm][r];
                    const float f = am[mm] * __expf(20.f*cv);
                    fm[mm][r] = f;
                    S[mm][r] += f;
                    L[mm][r] += __expf(invg*cv);
                }
            #pragma unroll
            for (int r=0;r<4;++r){
                DP[0][r] = fmaf(fm[0][r], c[1][r], DP[0][r]);
                DP[1][r] = fmaf(fm[1][r], c[0][r], DP[1][r]);
                const float c34 = c[3][r]+c[4][r];
                const float c24 = c[2][r]+c[4][r];
                const float c23 = c[2][r]+c[3][r];
                DP[2][r] = fmaf(fm[2][r], c34, DP[2][r]);
                DP[3][r] = fmaf(fm[3][r], c24, DP[3][r]);
                DP[4][r] = fmaf(fm[4][r], c23, DP[4][r]);
            }
        }
        #pragma unroll
        for (int off=8; off>=1; off>>=1)
            #pragma unroll
            for (int mm=0;mm<5;++mm)
                #pragma unroll
                for (int r=0;r<4;++r){
                    S[mm][r]  += __shfl_xor(S[mm][r],  off, 64);
                    L[mm][r]  += __shfl_xor(L[mm][r],  off, 64);
                    DP[mm][r] += __shfl_xor(DP[mm][r], off, 64);
                }
        #pragma unroll
        for (int r=0;r<4;++r){
            const float u =
                0.5f*(DP[0][r]*__builtin_amdgcn_rcpf(S[0][r])
                    + DP[1][r]*__builtin_amdgcn_rcpf(S[1][r]))
              + (1.f/6.f)*(DP[2][r]*__builtin_amdgcn_rcpf(S[2][r])
                         + DP[3][r]*__builtin_amdgcn_rcpf(S[3][r])
                         + DP[4][r]*__builtin_amdgcn_rcpf(S[4][r]));
            const float Lr =
                0.5f*(__logf(L[0][r]) + __logf(L[1][r]))
              + (1.f/3.f)*(__logf(L[2][r]) + __logf(L[3][r]) + __logf(L[4][r]));
            wacc += Lr - invg*u;
        }
    }
    wacc += __shfl_xor(wacc, 16, 64);
    wacc += __shfl_xor(wacc, 32, 64);
    if (lane == 0) atomicAdd(out, wacc * (1.0f/16384.0f));
}

// ---------------------------------------------------------------------------
extern "C" void kernel_launch(void* const* d_in, const int* in_sizes, int n_in,
                              void* d_out, int out_size, void* d_ws, size_t ws_size,
                              hipStream_t stream)
{
    const float* ue    = (const float*)d_in[0];
    const float* ie    = (const float*)d_in[1];
    const float* me    = (const float*)d_in[2];
    const float* te    = (const float*)d_in[3];
    const int*   users = (const int*)d_in[4];
    const int*   items = (const int*)d_in[5];
    const float* wfeat = (const float*)d_in[6];
    const float* wii   = (const float*)d_in[7];
    const float* gamma = (const float*)d_in[8];
    float* out = (float*)d_out;

    // ws: A_norm bf16 [4][16384][64] (8 MB) | W_norm bf16 [2][256][64] | cs[3][5][256] f32
    ushort_t* An = (ushort_t*)d_ws;
    ushort_t* Wn = An + (size_t)4*BATCH*DIM;
    float* cs  = (float*)(Wn + 2*KCODE*DIM);
    float* cs1 = cs;
    float* cs2 = cs + 1280;
    float* cs3 = cs + 2560;

    hipMemsetAsync(out, 0, sizeof(float), stream);
    hipMemsetAsync(cs, 0, 3*1280*sizeof(float), stream);

    k1_prep_gemm_cs1<<<dim3(256,5), 256, 0, stream>>>(
        ue, ie, me, te, users, items, wfeat, wii, An, Wn, cs1);
    k_pass<<<dim3(128,5), 256, 0, stream>>>(An, Wn, cs1, cs2);
    k_pass<<<dim3(128,5), 256, 0, stream>>>(An, Wn, cs2, cs3);
    k_ce<<<256, 256, 0, stream>>>(An, Wn, cs3, gamma, out);
}